// Round 4
// baseline (83.481 us; speedup 1.0000x reference)
//
#include <hip/hip_runtime.h>
#include <stdint.h>

// Problem constants: z (32,64,32,32) fp32, codebook (1024,64) fp32
#define NUM_E     1024
#define DIM       64
#define NPOS      32768      // 32*32*32 spatial positions
#define OUT_ELEMS 2097152    // 32*64*32*32

typedef short  short8  __attribute__((ext_vector_type(8)));   // 8 bf16 = 4 VGPRs
typedef float  f32x4   __attribute__((ext_vector_type(4)));

__device__ __forceinline__ unsigned int bf16r(float f) {
    uint32_t u = __builtin_bit_cast(uint32_t, f);
    return (u + 0x8000u) >> 16;            // round-half-up
}
__device__ __forceinline__ unsigned int pack2(float a, float b) {
    return bf16r(a) | (bf16r(b) << 16);
}

// ---------------- prep: bf16 codebook + biased norm (1 - 0.5*||c||^2) ----------------
// 64 blocks x 256 threads; 16 lanes per codebook row; float4 coalesced loads.
__global__ __launch_bounds__(256) void vq_prep(const float* __restrict__ cb,
                                               unsigned short* __restrict__ cbb,
                                               float* __restrict__ g0b,
                                               float* __restrict__ loss_out) {
    const int tid  = threadIdx.x;
    const int lane = tid & 63;
    const int w    = tid >> 6;
    const int quad = lane >> 4, r16 = lane & 15;
    const int row  = blockIdx.x * 16 + w * 4 + quad;
    if (blockIdx.x == 0 && tid == 0) loss_out[0] = 0.0f;   // d_out poisoned 0xAA pre-launch

    const float4 v = *reinterpret_cast<const float4*>(cb + row * 64 + r16 * 4);
    float s = v.x * v.x + v.y * v.y + v.z * v.z + v.w * v.w;
#pragma unroll
    for (int d = 1; d < 16; d <<= 1) s += __shfl_xor(s, d, 64);  // sum within 16-lane row group
    if (r16 == 0) g0b[row] = 1.0f - 0.5f * s;   // +1 bias keeps scores positive (uint-key trick)

    uint2 p;
    p.x = pack2(v.x, v.y);
    p.y = pack2(v.z, v.w);
    *reinterpret_cast<uint2*>(cbb + row * 64 + r16 * 4) = p;
}

// ---------------- main: LDS-staged z + MFMA distances + argmax-key + gather + loss ----------------
// Block: 512 threads (8 waves) = 64 consecutive positions; wave w scans entries [128w, 128w+128).
// 512 blocks x 2/CU -> 16 waves/CU (4/SIMD) for latency hiding; B/g0b prefetched one iter ahead.
// Score g = z.c - 0.5||c||^2 + 1 (max <=> min dist; +1 => positive => uint cmp == float cmp).
// Key = (g_bits & ~0x3FF) | (1023-idx): one v_and_or_b32 + one v_max_u32 per element.
#define ZP 68   // LDS row stride (floats): 64 + 4 pad — 16B-aligned, breaks pow-2 bank aliasing
__global__ __launch_bounds__(512, 4) void vq_main(
    const float* __restrict__ z,
    const float* __restrict__ cb,            // fp32 codebook (exact gather)
    const unsigned short* __restrict__ cbb,  // bf16 codebook
    const float* __restrict__ g0b,           // 1 - 0.5*||c_k||^2
    float* __restrict__ out,
    float* __restrict__ loss_out)
{
    const int tid  = threadIdx.x;
    const int lane = tid & 63;
    const int w    = __builtin_amdgcn_readfirstlane(tid >> 6);  // 0..7, wave-uniform
    const int quad = lane >> 4;
    const int r16  = lane & 15;

    const int n0    = blockIdx.x * 64;           // first position of this block
    const int b     = n0 >> 10;                  // batch (64 | 1024: tiles never cross batches)
    const int zbase = b * 65536 + (n0 & 1023);   // float index of (b, c=0, hw0)

    __shared__ float zt[64][ZP];                 // [position][channel], exact fp32
    __shared__ unsigned int cand[8][64];
    __shared__ float lsum[8];

    // ---- stage block's 16KB z-tile: coalesced float4 global loads, transposed LDS writes
#pragma unroll
    for (int p = 0; p < 2; ++p) {
        const int cc = p * 32 + (tid >> 4);      // channel 0..63
        const int f4 = tid & 15;                 // position quad 0..15
        const float4 v = *reinterpret_cast<const float4*>(z + zbase + cc * 1024 + f4 * 4);
        zt[f4 * 4 + 0][cc] = v.x;
        zt[f4 * 4 + 1][cc] = v.y;
        zt[f4 * 4 + 2][cc] = v.z;
        zt[f4 * 4 + 3][cc] = v.w;
    }
    __syncthreads();

    // ---- A fragments from LDS: A[m=r16][k=quad*8+j], m-position = pt*16+r16
    short8 afrag[4][2];
#pragma unroll
    for (int pt = 0; pt < 4; ++pt) {
#pragma unroll
        for (int half = 0; half < 2; ++half) {
            const float* src = &zt[pt * 16 + r16][quad * 8 + half * 32];
            const float4 a0 = *reinterpret_cast<const float4*>(src);
            const float4 a1 = *reinterpret_cast<const float4*>(src + 4);
            union { short8 s; uint32_t u[4]; } fr;
            fr.u[0] = pack2(a0.x, a0.y);
            fr.u[1] = pack2(a0.z, a0.w);
            fr.u[2] = pack2(a1.x, a1.y);
            fr.u[3] = pack2(a1.z, a1.w);
            afrag[pt][half] = fr.s;
        }
    }

    // ---- scan this wave's 128-entry slice in 16-entry tiles, B/g0b prefetched 1 iter ahead
    const int e0 = w * 128;
    unsigned int best[4][4];
#pragma unroll
    for (int pt = 0; pt < 4; ++pt)
#pragma unroll
        for (int r = 0; r < 4; ++r) best[pt][r] = 0u;

    const unsigned short* bptr = cbb + (e0 + r16) * 64 + quad * 8;
    short8 nb0 = *reinterpret_cast<const short8*>(bptr);
    short8 nb1 = *reinterpret_cast<const short8*>(bptr + 32);
    float   ng = g0b[e0 + r16];

#pragma unroll
    for (int it = 0; it < 8; ++it) {
        const short8 bf0 = nb0, bf1 = nb1;
        const float  nh  = ng;
        const int ecol = e0 + it * 16 + r16;
        const unsigned int idxenc = (unsigned int)(1023 - ecol);
        if (it < 7) {                                   // prefetch next tile's B + norm
            const unsigned short* np = cbb + (ecol + 16) * 64 + quad * 8;
            nb0 = *reinterpret_cast<const short8*>(np);
            nb1 = *reinterpret_cast<const short8*>(np + 32);
            ng  = g0b[ecol + 16];
        }
        f32x4 cvec = {nh, nh, nh, nh};
#pragma unroll
        for (int pt = 0; pt < 4; ++pt) {
            f32x4 acc = __builtin_amdgcn_mfma_f32_16x16x32_bf16(afrag[pt][0], bf0, cvec, 0, 0, 0);
            acc = __builtin_amdgcn_mfma_f32_16x16x32_bf16(afrag[pt][1], bf1, acc, 0, 0, 0);
            // C/D layout: col = lane&15 (entry), row = quad*4 + r (position)
#pragma unroll
            for (int r = 0; r < 4; ++r) {
                unsigned int k = (__builtin_bit_cast(unsigned int, acc[r]) & 0xFFFFFC00u) | idxenc;
                best[pt][r] = best[pt][r] > k ? best[pt][r] : k;   // v_max_u32
            }
        }
    }

    // ---- cross-lane max within each 16-lane group (keys carry the index)
#pragma unroll
    for (int pt = 0; pt < 4; ++pt) {
#pragma unroll
        for (int r = 0; r < 4; ++r) {
            unsigned int key = best[pt][r];
#pragma unroll
            for (int d = 1; d < 16; d <<= 1) {
                unsigned int o = __shfl_xor(key, d, 64);
                key = (o > key) ? o : key;
            }
            if (r16 == 0) cand[w][pt * 16 + quad * 4 + r] = key;   // index = position in tile
        }
    }
    __syncthreads();

    // ---- combine the 8 wave-slices; lane picks position n0+lane's winner
    unsigned int fk = cand[0][lane];
#pragma unroll
    for (int i = 1; i < 8; ++i) {
        const unsigned int o = cand[i][lane];
        fk = o > fk ? o : fk;
    }
    const int widx = 1023 - (int)(fk & 1023u);

    // ---- gather exact fp32 codebook row; z from LDS (exact); coalesced out; fused loss
    float ls = 0.0f;
#pragma unroll
    for (int i4 = 0; i4 < 2; ++i4) {
        const int c = w * 8 + i4 * 4;
        const float4 cv = *reinterpret_cast<const float4*>(cb + widx * 64 + c);
        const float4 zl = *reinterpret_cast<const float4*>(&zt[lane][c]);
        const float q4[4] = {cv.x, cv.y, cv.z, cv.w};
        const float z4[4] = {zl.x, zl.y, zl.z, zl.w};
#pragma unroll
        for (int j = 0; j < 4; ++j) {
            out[zbase + (c + j) * 1024 + lane] = q4[j];   // lane <-> position n0+lane
            const float d = q4[j] - z4[j];
            ls += d * d;
        }
    }
    // wave reduce, then one atomic per block
#pragma unroll
    for (int d = 1; d < 64; d <<= 1) ls += __shfl_xor(ls, d, 64);
    if (lane == 0) lsum[w] = ls;
    __syncthreads();
    if (tid == 0) {
        float t = 0.0f;
#pragma unroll
        for (int i = 0; i < 8; ++i) t += lsum[i];
        atomicAdd(loss_out, t * (1.25f / (float)OUT_ELEMS));
    }
}

extern "C" void kernel_launch(void* const* d_in, const int* in_sizes, int n_in,
                              void* d_out, int out_size, void* d_ws, size_t ws_size,
                              hipStream_t stream) {
    const float* z  = (const float*)d_in[0];   // (32,64,32,32) fp32
    const float* cb = (const float*)d_in[1];   // (1024,64) fp32
    unsigned short* cbb = (unsigned short*)d_ws;                       // 128 KB bf16 codebook
    float* g0b  = (float*)((char*)d_ws + NUM_E * DIM * sizeof(unsigned short)); // 4 KB biased norms
    float* out  = (float*)d_out;               // zq (2097152) then loss (1)
    float* loss = out + OUT_ELEMS;

    vq_prep<<<NUM_E / 16, 256, 0, stream>>>(cb, cbb, g0b, loss);
    vq_main<<<NPOS / 64, 512, 0, stream>>>(z, cb, cbb, g0b, out, loss);
}